// Round 5
// baseline (2428.576 us; speedup 1.0000x reference)
//
#include <hip/hip_runtime.h>
#include <hip/hip_fp16.h>
#include <cstdio>

// EmbeddingCellLSTM: B=32, S=2048, IN=64, EMB=32, H=256, 4H=1024
//  k1 pack_kernel : W_hh fp32 -> i8 (scale 2032) A-fragments for mfma_i32_16x16x64_i8.
//  k2 zx_kernel   : zx[b][s][row] = (concat(x,emb) @ W_ih^T + b) fp16, natural row order.
//  k3 lstm_kernel : 32 blocks (1/batch) x 1024 thr (16 waves), W_hh fully register-
//                   resident (64 regs/thread i8). Per step: z = Whh*h via 256 i8 MFMAs
//                   (N=1 broadcast, 1306 cyc/step/CU floor). Epilogue: D cols are
//                   replicas -> lane (q,n) holds rows q*4+r of ALL 4 gate tiles, so
//                   the 4 gates of unit q*4+(n&3) are in-lane: no bpermute. zx is
//                   pre-gathered (4 loads/lane) and pre-scaled by -sc one step ahead
//                   (off critical path); out store happens after the barrier (overlaps
//                   next MFMA phase). 1 __syncthreads()/step, i8 h feedback in 512B
//                   double-buffered LDS. ~121 regs @ 4 waves/SIMD -> no spill.

#define WPK_OFF (134217728u)   // zx = 32*2048*1024*2 bytes, then wpk 256 KB

typedef int v4i __attribute__((ext_vector_type(4)));

static __device__ __forceinline__ unsigned short f16bits(float v) {
  _Float16 h = (_Float16)v;
  return __builtin_bit_cast(unsigned short, h);
}

// ---------------- k1: pack W_hh -> i8 MFMA A-fragments ----------------
// tile = g*4+c ; thread t -> w=t>>6, lane: m=lane&15 (row), q=lane>>4
// A[m][k]: k = c*64 + q*16 + j (j=0..15, byte j of the 16B frag)
// row = g*256 + 16w + m ; wq = rint(w * 2032), |w| < 1/16 -> |wq| <= 127
__global__ __launch_bounds__(1024) void pack_kernel(const float* __restrict__ Whh,
                                                    uint4* __restrict__ wpk) {
  int tile = blockIdx.x;            // 0..15
  int g = tile >> 2, c = tile & 3;
  int t = threadIdx.x;
  int w = t >> 6, lane = t & 63, m = lane & 15, q = lane >> 4;
  int row = g * 256 + w * 16 + m;
  const float* src = Whh + row * 256 + c * 64 + q * 16;
  unsigned int pk[4];
#pragma unroll
  for (int d = 0; d < 4; d++) {
    unsigned int v = 0;
#pragma unroll
    for (int e = 0; e < 4; e++) {
      int qv = (int)rintf(src[d * 4 + e] * 2032.0f);
      v |= ((unsigned int)(qv & 255)) << (8 * e);
    }
    pk[d] = v;
  }
  uint4 o; o.x = pk[0]; o.y = pk[1]; o.z = pk[2]; o.w = pk[3];
  wpk[tile * 1024 + t] = o;
}

// ---------------- k2: zx = concat(x,emb) @ W_ih^T + b (fp16, natural row order) ----------------
__global__ __launch_bounds__(256) void zx_kernel(const float* __restrict__ x,
                                                 const float* __restrict__ emb,
                                                 const float* __restrict__ Wih,
                                                 const float* __restrict__ bias,
                                                 unsigned short* __restrict__ zx) {
  __shared__ __align__(16) float XeT[96][68];
  __shared__ __align__(16) float WT[96][68];
  int mt = blockIdx.x, nt = blockIdx.y;     // 1024 x 16
  int m0 = mt * 64, n0 = nt * 64;
  int tid = threadIdx.x;
  for (int idx = tid; idx < 6144; idx += 256) {
    int r = idx / 96, k = idx - r * 96;
    size_t m = (size_t)(m0 + r);
    float v = (k < 64) ? x[m * 64 + k] : emb[m * 32 + (k - 64)];
    XeT[k][r] = v;
  }
  for (int idx = tid; idx < 6144; idx += 256) {
    int c = idx / 96, k = idx - c * 96;
    WT[k][c] = Wih[(size_t)(n0 + c) * 96 + k];
  }
  __syncthreads();
  int ty = tid >> 4, tx = tid & 15;
  int r0 = ty * 4, c0 = tx * 4;
  float acc[4][4] = {};
  for (int k = 0; k < 96; k++) {
    float4 a = *(const float4*)&XeT[k][r0];
    float4 w = *(const float4*)&WT[k][c0];
    float av[4] = {a.x, a.y, a.z, a.w};
    float wv[4] = {w.x, w.y, w.z, w.w};
#pragma unroll
    for (int i = 0; i < 4; i++)
#pragma unroll
      for (int jj = 0; jj < 4; jj++) acc[i][jj] += av[i] * wv[jj];
  }
#pragma unroll
  for (int i = 0; i < 4; i++) {
    size_t m = (size_t)(m0 + r0 + i);
#pragma unroll
    for (int jj = 0; jj < 4; jj++) {
      int col = n0 + c0 + jj;
      zx[m * 1024 + (size_t)col] = f16bits(acc[i][jj] + bias[col]);
    }
  }
}

// ---------------- k3: persistent per-batch LSTM (i8 MFMA, in-lane epilogue) ----------------
__global__ __launch_bounds__(1024, 4) void lstm_kernel(const unsigned short* __restrict__ zx,
                                                       const v4i* __restrict__ wpk,
                                                       float* __restrict__ out) {
  __shared__ __align__(16) char hq[2][256];
  const int t = threadIdx.x, b = blockIdx.x;
  const int w = t >> 6, lane = t & 63, q = lane >> 4, n = lane & 15;
  const int m = n & 3;                 // unit-within-quad this lane processes
  const int j = w * 16 + q * 4 + m;    // global hidden unit (4 replica lanes per unit)

  // full W_hh residency: 16 frags x 16B i8 = 64 regs (A-operand, AGPR-friendly)
  v4i wf[16];
#pragma unroll
  for (int i = 0; i < 16; i++) wf[i] = wpk[i * 1024 + t];

  if (t < 128) ((unsigned int*)hq)[t] = 0;   // zero both h buffers (2x256 i8)
  __syncthreads();

  const float dq = 1.0f / (2032.0f * 127.0f);
  const float kSig = -1.44269504f, kTan = -2.88539008f;
  const float c1 = kSig * dq, c2 = kTan * dq;
  const bool wrn = (n < 4);                  // replica-0 lanes write h/out

  // zx: 4 gate rows of unit j -> byte offsets g*512 off a common lane address
  const unsigned short* zp = zx + (size_t)b * (2048u * 1024u) + j;
  float* op = out + (size_t)b * (2048u * 256u) + j;

  // preload + pre-scale zx for s=0 (zxs_g = -sc_g * zx_g)
  float zxs0, zxs1, zxs2, zxs3;
  {
    zxs0 = kSig * (float)__builtin_bit_cast(_Float16, zp[0]);
    zxs1 = kSig * (float)__builtin_bit_cast(_Float16, zp[256]);
    zxs2 = kTan * (float)__builtin_bit_cast(_Float16, zp[512]);
    zxs3 = kSig * (float)__builtin_bit_cast(_Float16, zp[768]);
  }

  float cc = 0.f, hprev = 0.f;

  for (int s = 0; s < 2048; s++) {
    // issue next-step zx loads (latency hidden under this step's MFMA phase)
    int sp = s + 1; if (sp > 2047) sp = 2047;
    const unsigned short* zn = zp + ((size_t)sp << 10);
    unsigned short nr0 = zn[0], nr1 = zn[256], nr2 = zn[512], nr3 = zn[768];

    // store previous step's h (off critical path, overlaps MFMA)
    if (wrn && s > 0) op[(size_t)(s - 1) * 256] = hprev;

    // B-frags: broadcast h chunk (16B per 16-lane group -> all N cols = h)
    const char* hc = hq[s & 1];
    v4i bq[4];
#pragma unroll
    for (int c = 0; c < 4; c++) bq[c] = *(const v4i*)(hc + c * 64 + q * 16);

    v4i acc[4];
    const v4i zero = {0, 0, 0, 0};
#pragma unroll
    for (int gg = 0; gg < 4; gg++) acc[gg] = zero;
#pragma unroll
    for (int c = 0; c < 4; c++)
#pragma unroll
      for (int gg = 0; gg < 4; gg++)
        acc[gg] = __builtin_amdgcn_mfma_i32_16x16x64_i8(wf[gg * 4 + c], bq[c], acc[gg], 0, 0, 0);

    // in-lane gate select: lane holds rows q*4+r of every gate tile; pick r=m
    auto sel = [&](v4i v) -> int {
      int a = (m & 1) ? v[1] : v[0];
      int c = (m & 1) ? v[3] : v[2];
      return (m & 2) ? c : a;
    };
    float zi = (float)sel(acc[0]);
    float zf = (float)sel(acc[1]);
    float zg = (float)sel(acc[2]);
    float zo = (float)sel(acc[3]);

    // activations (exp2-form, dq folded into fma coefficient)
    float ei = __builtin_amdgcn_exp2f(fmaf(zi, c1, zxs0));
    float ai = __builtin_amdgcn_rcpf(1.f + ei);
    float ef = __builtin_amdgcn_exp2f(fmaf(zf, c1, zxs1));
    float af = __builtin_amdgcn_rcpf(1.f + ef);
    float eg = __builtin_amdgcn_exp2f(fmaf(zg, c2, zxs2));
    float ag = fmaf(2.f, __builtin_amdgcn_rcpf(1.f + eg), -1.f);
    float eo = __builtin_amdgcn_exp2f(fmaf(zo, c1, zxs3));
    float ao = __builtin_amdgcn_rcpf(1.f + eo);

    float cn = fmaf(af, cc, ai * ag);
    float et = __builtin_amdgcn_exp2f(kTan * cn);
    float th = fmaf(2.f, __builtin_amdgcn_rcpf(1.f + et), -1.f);
    float h = ao * th;
    cc = cn;
    hprev = h;

    // pre-scale next step's zx (loads issued ~1 step ago; off critical path)
    zxs0 = kSig * (float)__builtin_bit_cast(_Float16, nr0);
    zxs1 = kSig * (float)__builtin_bit_cast(_Float16, nr1);
    zxs2 = kTan * (float)__builtin_bit_cast(_Float16, nr2);
    zxs3 = kSig * (float)__builtin_bit_cast(_Float16, nr3);

    // i8 h feedback (replica-0 lanes), then the one barrier
    if (wrn) hq[(s & 1) ^ 1][j] = (char)(int)rintf(h * 127.0f);
    __syncthreads();
  }
  if (wrn) {
    op[(size_t)2047 * 256] = hprev;
    out[16777216u + (size_t)b * 256 + j] = hprev;          // final h
    out[16777216u + 8192u + (size_t)b * 256 + j] = cc;     // final c
  }
}

extern "C" void kernel_launch(void* const* d_in, const int* in_sizes, int n_in,
                              void* d_out, int out_size, void* d_ws, size_t ws_size,
                              hipStream_t stream) {
  const float* x = (const float*)d_in[0];
  const float* emb = (const float*)d_in[1];
  const float* W_ih = (const float*)d_in[2];
  const float* W_hh = (const float*)d_in[3];
  const float* bias = (const float*)d_in[4];
  float* out = (float*)d_out;
  char* ws = (char*)d_ws;

  unsigned short* zx = (unsigned short*)ws;
  uint4* wpk = (uint4*)(ws + WPK_OFF);

  size_t need = (size_t)WPK_OFF + 262144u;
  if (ws_size < need) {
    fprintf(stderr, "kernel_launch: ws too small: %zu < %zu\n", ws_size, need);
  }

  pack_kernel<<<dim3(16), dim3(1024), 0, stream>>>(W_hh, wpk);
  zx_kernel<<<dim3(1024, 16), dim3(256), 0, stream>>>(x, emb, W_ih, bias, zx);
  lstm_kernel<<<dim3(32), dim3(1024), 0, stream>>>(zx, (const v4i*)wpk, out);
}

// Round 6
// 2036.120 us; speedup vs baseline: 1.1927x; 1.1927x over previous
//
#include <hip/hip_runtime.h>
#include <hip/hip_fp16.h>
#include <cstdio>

// EmbeddingCellLSTM: B=32, S=2048, IN=64, EMB=32, H=256, 4H=1024
//  k1 pack_kernel : W_hh fp32 -> i8 (scale 2032) A-fragments for mfma_i32_16x16x64_i8.
//  k2 zx_kernel   : zx[b][s][unit*4+gate] = -sc_g * (concat(x,emb) @ W_ih^T + b) as fp16
//                   (pre-scaled for exp2-form activations; 4 gates contiguous per unit).
//  k3 lstm_kernel : 32 blocks (1/batch) x 1024 thr (16 waves), W_hh fully register-
//                   resident (64 regs/thread i8). Per step: z = Whh*h via 256 i8 MFMAs
//                   (N=1 broadcast; 1306 cyc/step/CU floor). Epilogue: D cols are
//                   replicas -> lane holds rows q*4+r of ALL 4 gate tiles: 4 gates of
//                   unit j=w*16+q*4+(n&3) selected in-lane (no bpermute). zx: ONE
//                   dwordx2/lane/step, prefetched 2 steps ahead (za8/zb8/zc8). out
//                   store issued post-barrier (retires under next MFMA phase, off the
//                   vmcnt(0) barrier drain). 1 __syncthreads()/step, i8 h feedback in
//                   512B double-buffered LDS. No spills @ 4 waves/SIMD.

#define WPK_OFF (134217728u)   // zx = 32*2048*1024*2 bytes, then wpk 256 KB

typedef int v4i __attribute__((ext_vector_type(4)));

static __device__ __forceinline__ unsigned short f16bits(float v) {
  _Float16 h = (_Float16)v;
  return __builtin_bit_cast(unsigned short, h);
}
static __device__ __forceinline__ float f16val(unsigned short u) {
  return (float)__builtin_bit_cast(_Float16, u);
}

// ---------------- k1: pack W_hh -> i8 MFMA A-fragments ----------------
// tile = g*4+c ; thread t -> w=t>>6, lane: m=lane&15 (row), q=lane>>4
// A[m][k]: k = c*64 + q*16 + j (j=0..15, byte j of the 16B frag)
// row = g*256 + 16w + m ; wq = rint(w * 2032), |w| < 1/16 -> |wq| <= 127
__global__ __launch_bounds__(1024) void pack_kernel(const float* __restrict__ Whh,
                                                    uint4* __restrict__ wpk) {
  int tile = blockIdx.x;            // 0..15
  int g = tile >> 2, c = tile & 3;
  int t = threadIdx.x;
  int w = t >> 6, lane = t & 63, m = lane & 15, q = lane >> 4;
  int row = g * 256 + w * 16 + m;
  const float* src = Whh + row * 256 + c * 64 + q * 16;
  unsigned int pk[4];
#pragma unroll
  for (int d = 0; d < 4; d++) {
    unsigned int v = 0;
#pragma unroll
    for (int e = 0; e < 4; e++) {
      int qv = (int)rintf(src[d * 4 + e] * 2032.0f);
      v |= ((unsigned int)(qv & 255)) << (8 * e);
    }
    pk[d] = v;
  }
  uint4 o; o.x = pk[0]; o.y = pk[1]; o.z = pk[2]; o.w = pk[3];
  wpk[tile * 1024 + t] = o;
}

// ---------------- k2: zx = -sc_g*(concat(x,emb) @ W_ih^T + b)  fp16, [unit][gate] ----------------
__global__ __launch_bounds__(256) void zx_kernel(const float* __restrict__ x,
                                                 const float* __restrict__ emb,
                                                 const float* __restrict__ Wih,
                                                 const float* __restrict__ bias,
                                                 unsigned short* __restrict__ zx) {
  __shared__ __align__(16) float XeT[96][68];
  __shared__ __align__(16) float WT[96][68];
  int mt = blockIdx.x, nt = blockIdx.y;     // 1024 x 16
  int m0 = mt * 64, n0 = nt * 64;
  int tid = threadIdx.x;
  for (int idx = tid; idx < 6144; idx += 256) {
    int r = idx / 96, k = idx - r * 96;
    size_t m = (size_t)(m0 + r);
    float v = (k < 64) ? x[m * 64 + k] : emb[m * 32 + (k - 64)];
    XeT[k][r] = v;
  }
  for (int idx = tid; idx < 6144; idx += 256) {
    int c = idx / 96, k = idx - c * 96;
    WT[k][c] = Wih[(size_t)(n0 + c) * 96 + k];
  }
  __syncthreads();
  int ty = tid >> 4, tx = tid & 15;
  int r0 = ty * 4, c0 = tx * 4;
  float acc[4][4] = {};
  for (int k = 0; k < 96; k++) {
    float4 a = *(const float4*)&XeT[k][r0];
    float4 w = *(const float4*)&WT[k][c0];
    float av[4] = {a.x, a.y, a.z, a.w};
    float wv[4] = {w.x, w.y, w.z, w.w};
#pragma unroll
    for (int i = 0; i < 4; i++)
#pragma unroll
      for (int jj = 0; jj < 4; jj++) acc[i][jj] += av[i] * wv[jj];
  }
  int g = n0 >> 8;   // whole 64-col tile lies in one gate block
  const float scg = (g == 2) ? -2.88539008f : -1.44269504f;
#pragma unroll
  for (int i = 0; i < 4; i++) {
    size_t m = (size_t)(m0 + r0 + i);
#pragma unroll
    for (int jj = 0; jj < 4; jj++) {
      int col = n0 + c0 + jj;
      int ju = col & 255;
      zx[m * 1024 + (size_t)(ju * 4 + g)] = f16bits(scg * (acc[i][jj] + bias[col]));
    }
  }
}

// ---------------- k3: persistent per-batch LSTM (i8 MFMA, in-lane epilogue) ----------------
__global__ __launch_bounds__(1024, 4) void lstm_kernel(const unsigned short* __restrict__ zx,
                                                       const v4i* __restrict__ wpk,
                                                       float* __restrict__ out) {
  __shared__ __align__(16) char hq[2][256];
  const int t = threadIdx.x, b = blockIdx.x;
  const int w = t >> 6, lane = t & 63, q = lane >> 4, n = lane & 15;
  const int m = n & 3;                 // unit-within-quad this lane processes
  const int j = w * 16 + q * 4 + m;    // global hidden unit (4 replica lanes per unit)

  // full W_hh residency: 16 frags x 16B i8 = 64 regs (A-operand, AGPR-friendly)
  v4i wf[16];
#pragma unroll
  for (int i = 0; i < 16; i++) wf[i] = wpk[i * 1024 + t];

  if (t < 128) ((unsigned int*)hq)[t] = 0;   // zero both h buffers (2x256 i8)
  __syncthreads();

  const float dq = 1.0f / (2032.0f * 127.0f);
  const float kSig = -1.44269504f, kTan = -2.88539008f;
  const float c1 = kSig * dq, c2 = kTan * dq;
  const bool wrn = (n < 4);                  // replica-0 lanes write h/out

  // zx: the 4 pre-scaled gate values of unit j are 8 contiguous bytes
  const unsigned short* zq = zx + (size_t)b * (2048u * 1024u) + (size_t)j * 4;
  float* op = out + (size_t)b * (2048u * 256u) + j;

  // 2-deep prefetch (s=0, s=1)
  uint2 za8 = *(const uint2*)zq;
  uint2 zb8 = *(const uint2*)(zq + 1024);

  float cc = 0.f, hprev = 0.f;

  for (int s = 0; s < 2048; s++) {
    // previous step's out store: post-barrier, retires under this step's MFMAs
    if (wrn && s > 0) op[(size_t)(s - 1) * 256] = hprev;
    // prefetch s+2 (~2 steps of slack >> HBM latency)
    int sp = s + 2; if (sp > 2047) sp = 2047;
    uint2 zc8 = *(const uint2*)(zq + ((size_t)sp << 10));

    // B-frags: broadcast h chunk (16B per 16-lane group -> all N cols = h)
    const char* hc = hq[s & 1];
    v4i bq[4];
#pragma unroll
    for (int c = 0; c < 4; c++) bq[c] = *(const v4i*)(hc + c * 64 + q * 16);

    v4i acc[4];
    const v4i zero = {0, 0, 0, 0};
#pragma unroll
    for (int gg = 0; gg < 4; gg++) acc[gg] = zero;
#pragma unroll
    for (int c = 0; c < 4; c++)
#pragma unroll
      for (int gg = 0; gg < 4; gg++)
        acc[gg] = __builtin_amdgcn_mfma_i32_16x16x64_i8(wf[gg * 4 + c], bq[c], acc[gg], 0, 0, 0);

    // in-lane gate select: lane holds rows q*4+r of every gate tile; pick r=m
    auto sel = [&](v4i v) -> int {
      int a = (m & 1) ? v[1] : v[0];
      int c = (m & 1) ? v[3] : v[2];
      return (m & 2) ? c : a;
    };
    float zi = (float)sel(acc[0]);
    float zf = (float)sel(acc[1]);
    float zg = (float)sel(acc[2]);
    float zo = (float)sel(acc[3]);

    // unpack pre-scaled zx (zxs_g = -sc_g * zx_g, done in k2)
    float zxs0 = f16val((unsigned short)(za8.x & 0xffff));
    float zxs1 = f16val((unsigned short)(za8.x >> 16));
    float zxs2 = f16val((unsigned short)(za8.y & 0xffff));
    float zxs3 = f16val((unsigned short)(za8.y >> 16));

    // activations (exp2-form, dq folded into fma coefficient)
    float ei = __builtin_amdgcn_exp2f(fmaf(zi, c1, zxs0));
    float ai = __builtin_amdgcn_rcpf(1.f + ei);
    float ef = __builtin_amdgcn_exp2f(fmaf(zf, c1, zxs1));
    float af = __builtin_amdgcn_rcpf(1.f + ef);
    float eg = __builtin_amdgcn_exp2f(fmaf(zg, c2, zxs2));
    float ag = fmaf(2.f, __builtin_amdgcn_rcpf(1.f + eg), -1.f);
    float eo = __builtin_amdgcn_exp2f(fmaf(zo, c1, zxs3));
    float ao = __builtin_amdgcn_rcpf(1.f + eo);

    float cn = fmaf(af, cc, ai * ag);
    float et = __builtin_amdgcn_exp2f(kTan * cn);
    float th = fmaf(2.f, __builtin_amdgcn_rcpf(1.f + et), -1.f);
    float h = ao * th;
    cc = cn;
    hprev = h;

    za8 = zb8; zb8 = zc8;

    // i8 h feedback (replica-0 lanes), then the one barrier
    if (wrn) hq[(s & 1) ^ 1][j] = (char)(int)rintf(h * 127.0f);
    __syncthreads();
  }
  if (wrn) {
    op[(size_t)2047 * 256] = hprev;
    out[16777216u + (size_t)b * 256 + j] = hprev;          // final h
    out[16777216u + 8192u + (size_t)b * 256 + j] = cc;     // final c
  }
}

extern "C" void kernel_launch(void* const* d_in, const int* in_sizes, int n_in,
                              void* d_out, int out_size, void* d_ws, size_t ws_size,
                              hipStream_t stream) {
  const float* x = (const float*)d_in[0];
  const float* emb = (const float*)d_in[1];
  const float* W_ih = (const float*)d_in[2];
  const float* W_hh = (const float*)d_in[3];
  const float* bias = (const float*)d_in[4];
  float* out = (float*)d_out;
  char* ws = (char*)d_ws;

  unsigned short* zx = (unsigned short*)ws;
  uint4* wpk = (uint4*)(ws + WPK_OFF);

  size_t need = (size_t)WPK_OFF + 262144u;
  if (ws_size < need) {
    fprintf(stderr, "kernel_launch: ws too small: %zu < %zu\n", ws_size, need);
  }

  pack_kernel<<<dim3(16), dim3(1024), 0, stream>>>(W_hh, wpk);
  zx_kernel<<<dim3(1024, 16), dim3(256), 0, stream>>>(x, emb, W_ih, bias, zx);
  lstm_kernel<<<dim3(32), dim3(1024), 0, stream>>>(zx, (const v4i*)wpk, out);
}